// Round 17
// baseline (131.847 us; speedup 1.0000x reference)
//
#include <hip/hip_runtime.h>
#include <hip/hip_fp16.h>
#include <stdint.h>

// ---- types ----
typedef _Float16 h16;
typedef _Float16 h16x8 __attribute__((ext_vector_type(8)));
typedef float f32x4 __attribute__((ext_vector_type(4)));

#define BB 4
#define SS 2048
#define DD 1024

#define EPI_H16 0
#define EPI_DIV 2   // store fp32 C / rowsum[row]  (rowsum = raw row sums)

__device__ __forceinline__ void gload16(const void* g, void* l) {
    __builtin_amdgcn_global_load_lds(
        (const __attribute__((address_space(1))) uint32_t*)g,
        (__attribute__((address_space(3))) uint32_t*)l, 16, 0, 0);
}

// ---- fp32 -> fp16 convert for q (*0.125) and k; block 0 also zeroes rowsum ----
__global__ __launch_bounds__(256) void cvt_qk(
    const float* __restrict__ q, const float* __restrict__ k,
    h16* __restrict__ qh, h16* __restrict__ kh, float* __restrict__ rowsum) {
    if (blockIdx.x == 0) {
#pragma unroll
        for (int i = 0; i < 32; ++i) rowsum[threadIdx.x + i * 256] = 0.f;
    }
    int b = blockIdx.x;
    const float* src; h16* dst; float sc = 1.0f;
    if (b < 1024)      { src = q; dst = qh; sc = 0.125f; }
    else               { src = k; dst = kh; b -= 1024; }
    size_t base = (size_t)b * 2048 + threadIdx.x;
    float4 a[8];
#pragma unroll
    for (int i = 0; i < 8; ++i) a[i] = ((const float4*)src)[base + (size_t)i * 256];
#pragma unroll
    for (int i = 0; i < 8; ++i) {
        union { int2 i2; h16 h[4]; } u;
        u.h[0] = (h16)(a[i].x * sc); u.h[1] = (h16)(a[i].y * sc);
        u.h[2] = (h16)(a[i].z * sc); u.h[3] = (h16)(a[i].w * sc);
        ((int2*)dst)[base + (size_t)i * 256] = u.i2;
    }
}

__device__ __forceinline__ void cvt_store(h16* dst, size_t g, float4 a) {
    union { int2 i2; h16 h[4]; } u;
    u.h[0] = (h16)a.x; u.h[1] = (h16)a.y; u.h[2] = (h16)a.z; u.h[3] = (h16)a.w;
    ((int2*)dst)[g] = u.i2;
}

// ==== GEMM1 (round-12 verified gemm2p<256> body) + in-loop cvt(v,w) +
//      epilogue rowsum-atomics ====
// Ledger (counting loads AND stores, robust to compiler reordering of the
// plain cvt ops vs builtin stages):
//  - cvt ops issued AFTER the stage block -> at the mid wait they are the
//    2 YOUNGEST; the 2 oldest are the cvt pair aged one full iteration
//    (~2500 cy, retired) or Ah1 from the previous stage (needed now anyway).
//  - mid vmcnt(10): in-flight 12 -> retires exactly the 2 aged ops. No stall.
//  - end vmcnt(2): drains this iter's stage (Ah1(G+1) resident early = safe),
//    keeps the 2 young cvt ops in flight across the barrier.
__global__ __launch_bounds__(512, 2) void gemm1f(
    const h16* __restrict__ A, const h16* __restrict__ B, h16* __restrict__ C,
    const float* __restrict__ v, const float* __restrict__ w,
    h16* __restrict__ vh, h16* __restrict__ wh, float* __restrict__ rowsum)
{
    constexpr int ABYTES = 256 * 128;
    constexpr int BUFB   = 2 * ABYTES;
    __shared__ __align__(1024) char lds[2 * BUFB];   // 128 KB

    const int tid = threadIdx.x;
    const int gid = blockIdx.x;                      // 0..255
    const size_t tidg = (size_t)gid * 512 + tid;     // 0..131071

    const int wgid = (gid & 7) * 32 + (gid >> 3);    // XCD swizzle (256 wgs)
    const int bb  = wgid / 64;
    const int rem = wgid % 64;
    const int tm = rem / 8, tn = rem % 8;
    const int row0 = tm * 256, col0 = tn * 256;

    const h16* Ab = A + (long long)bb * ((long long)SS * DD);
    const h16* Bb = B + (long long)bb * ((long long)SS * DD);

    const int lane = tid & 63, wid = tid >> 6;
    const int wm = wid >> 2, wn = wid & 3;
    const int frow = lane & 15, kq = lane >> 4;

    const int NT = DD >> 6;   // 16

    f32x4 acc[8][4];
#pragma unroll
    for (int m = 0; m < 8; ++m)
#pragma unroll
        for (int n = 0; n < 4; ++n) acc[m][n] = (f32x4){0.f, 0.f, 0.f, 0.f};

    char* l0 = (char*)lds;

    auto STAGE_B = [&](int kt, int buf) {
#pragma unroll
        for (int i = 0; i < 4; ++i) {
            int d = i * 512 + tid;
            int s = d & 7, r = d >> 3;
            int gg = s ^ (r & 7);
            gload16(Bb + (size_t)(col0 + r) * DD + kt + gg * 8,
                    l0 + buf * BUFB + ABYTES + (r * 8 + s) * 16);
        }
    };
    auto STAGE_AH = [&](int kt, int buf, int mh) {
#pragma unroll
        for (int i = 0; i < 2; ++i) {
            int d = i * 512 + tid;
            int s = d & 7, hr = d >> 3;
            int r = ((hr & ~63) << 1) + mh * 64 + (hr & 63);
            int gg = s ^ (r & 7);
            gload16(Ab + (size_t)(row0 + r) * DD + kt + gg * 8,
                    l0 + buf * BUFB + (r * 8 + s) * 16);
        }
    };
    auto READ_A = [&](int buf, int mh, h16x8 (&af)[4][2]) {
#pragma unroll
        for (int mm = 0; mm < 4; ++mm)
#pragma unroll
            for (int ks = 0; ks < 2; ++ks) {
                int r = wm * 128 + (mh * 4 + mm) * 16 + frow;
                int s = (ks * 4 + kq) ^ (r & 7);
                af[mm][ks] = *(const h16x8*)(l0 + buf * BUFB + (r * 8 + s) * 16);
            }
    };
    auto READ_B = [&](int buf, h16x8 (&bf)[4][2]) {
#pragma unroll
        for (int nn = 0; nn < 4; ++nn)
#pragma unroll
            for (int ks = 0; ks < 2; ++ks) {
                int r = wn * 64 + nn * 16 + frow;
                int s = (ks * 4 + kq) ^ (r & 7);
                bf[nn][ks] = *(const h16x8*)(l0 + buf * BUFB + ABYTES + (r * 8 + s) * 16);
            }
    };
    auto MFMA_H = [&](int mh, h16x8 (&af)[4][2], h16x8 (&bf)[4][2]) {
        __builtin_amdgcn_s_setprio(1);
#pragma unroll
        for (int ks = 0; ks < 2; ++ks)
#pragma unroll
            for (int mm = 0; mm < 4; ++mm)
#pragma unroll
                for (int nn = 0; nn < 4; ++nn)
                    acc[mh * 4 + mm][nn] =
                        __builtin_amdgcn_mfma_f32_16x16x32_f16(
                            af[mm][ks], bf[nn][ks], acc[mh * 4 + mm][nn], 0, 0, 0);
        __builtin_amdgcn_s_setprio(0);
    };

    // ---- prologue: w cvt (2 float4/thread, oldest ops) + stage tile 0
    {
        float4 w0 = ((const float4*)w)[tidg];
        float4 w1 = ((const float4*)w)[131072 + tidg];
        cvt_store(wh, tidg, w0);
        cvt_store(wh, 131072 + tidg, w1);
    }
    STAGE_B(0, 0); STAGE_AH(0, 0, 0); STAGE_AH(0, 0, 1);
    asm volatile("s_waitcnt vmcnt(2)" ::: "memory");
    __builtin_amdgcn_s_barrier();

    h16x8 af[4][2], bf[4][2];
    float4 vbuf;   // one-iter rotation: load at iter G, store at iter G+1

    for (int G = 0; G < NT; ++G) {
        const int buf = G & 1;
        const int kt1 = (G + 1) << 6;
        if (G + 1 < NT) {
            STAGE_B(kt1, buf ^ 1);
            STAGE_AH(kt1, buf ^ 1, 0);
            STAGE_AH(kt1, buf ^ 1, 1);
        }
        // in-loop cvt of v: issued AFTER stage -> youngest in the queue;
        // waited on only one full iteration later (mid vmcnt(10)).
        float4 vnew = ((const float4*)v)[(size_t)G * 131072 + tidg];
        if (G > 0) cvt_store(vh, (size_t)(G - 1) * 131072 + tidg, vbuf);
        vbuf = vnew;
        READ_A(buf, 0, af);
        READ_B(buf, bf);
        MFMA_H(0, af, bf);
        if (G + 1 < NT) asm volatile("s_waitcnt vmcnt(10)" ::: "memory");
        else            asm volatile("s_waitcnt vmcnt(0)" ::: "memory");
        __builtin_amdgcn_s_barrier();
        READ_A(buf, 1, af);
        MFMA_H(1, af, bf);
        if (G + 1 >= NT) break;
        asm volatile("s_waitcnt vmcnt(2)" ::: "memory");
        __builtin_amdgcn_s_barrier();
    }
    // flush last v pair
    cvt_store(vh, (size_t)(NT - 1) * 131072 + tidg, vbuf);

    // ---- epilogue: E = exp(score-16) + per-row sum atomics
    h16* Cb = C + (long long)bb * ((long long)SS * SS);
    float* rs = rowsum + bb * SS;
    const int erow = row0 + wm * 128 + (lane >> 4) * 4;
    const int ecol = col0 + wn * 64 + (lane & 15);
#pragma unroll
    for (int m = 0; m < 8; ++m)
#pragma unroll
        for (int j = 0; j < 4; ++j) {
            const int row = erow + m * 16 + j;
            float p = 0.f;
#pragma unroll
            for (int n = 0; n < 4; ++n) {
                float e = __expf(acc[m][n][j] - 16.0f);
                Cb[(size_t)row * SS + (ecol + n * 16)] = (h16)e;
                p += e;
            }
            p += __shfl_xor(p, 1);
            p += __shfl_xor(p, 2);
            p += __shfl_xor(p, 4);
            p += __shfl_xor(p, 8);
            if ((lane & 15) == 0) atomicAdd(&rs[row], p);
        }
}

// ==== small GEMM (round-6/12 verified): 128x128, 4 waves, 2 blocks/CU ====
template<int EPI>
__global__ __launch_bounds__(256, 2) void gemm2p_sm(
    const h16* __restrict__ A, const h16* __restrict__ B, void* __restrict__ Cv,
    int lda, int ldb, int ldc, int K, int tilesN, int tilesMN,
    long long aBatch, long long bBatch, long long cBatch, const float* __restrict__ rowsum)
{
    constexpr int ABYTES = 128 * 128;
    constexpr int BBYTES = 128 * 128;
    constexpr int BUFB   = ABYTES + BBYTES;

    __shared__ __align__(1024) char lds[2 * BUFB];   // 64 KB

    const int tid = threadIdx.x;
    const int nwg = gridDim.x;
    const int bid = blockIdx.x;
    const int wgid = (bid & 7) * (nwg >> 3) + (bid >> 3);   // XCD swizzle
    const int bb  = wgid / tilesMN;
    const int rem = wgid % tilesMN;
    const int tm = rem / tilesN, tn = rem % tilesN;
    const int row0 = tm * 128, col0 = tn * 128;

    const h16* Ab = A + (long long)bb * aBatch;
    const h16* Bb = B + (long long)bb * bBatch;

    const int lane = tid & 63, wid = tid >> 6;
    const int wm = wid >> 1, wn = wid & 1;
    const int frow = lane & 15, kq = lane >> 4;

    const int NT = K >> 6;

    f32x4 acc[4][4];
#pragma unroll
    for (int m = 0; m < 4; ++m)
#pragma unroll
        for (int n = 0; n < 4; ++n) acc[m][n] = (f32x4){0.f, 0.f, 0.f, 0.f};

    char* l0 = (char*)lds;

    auto STAGE_B = [&](int kt, int buf) {
#pragma unroll
        for (int i = 0; i < 4; ++i) {
            int d = i * 256 + tid;
            int s = d & 7, r = d >> 3;
            int gg = s ^ (r & 7);
            gload16(Bb + (size_t)(col0 + r) * ldb + kt + gg * 8,
                    l0 + buf * BUFB + ABYTES + (r * 8 + s) * 16);
        }
    };
    auto STAGE_AH = [&](int kt, int buf, int mh) {
#pragma unroll
        for (int i = 0; i < 2; ++i) {
            int d = i * 256 + tid;
            int s = d & 7, hr = d >> 3;
            int r = ((hr & ~31) << 1) + mh * 32 + (hr & 31);
            int gg = s ^ (r & 7);
            gload16(Ab + (size_t)(row0 + r) * lda + kt + gg * 8,
                    l0 + buf * BUFB + (r * 8 + s) * 16);
        }
    };
    auto READ_A = [&](int buf, int mh, h16x8 (&af)[2][2]) {
#pragma unroll
        for (int mm = 0; mm < 2; ++mm)
#pragma unroll
            for (int ks = 0; ks < 2; ++ks) {
                int r = wm * 64 + (mh * 2 + mm) * 16 + frow;
                int s = (ks * 4 + kq) ^ (r & 7);
                af[mm][ks] = *(const h16x8*)(l0 + buf * BUFB + (r * 8 + s) * 16);
            }
    };
    auto READ_B = [&](int buf, h16x8 (&bf)[4][2]) {
#pragma unroll
        for (int nn = 0; nn < 4; ++nn)
#pragma unroll
            for (int ks = 0; ks < 2; ++ks) {
                int r = wn * 64 + nn * 16 + frow;
                int s = (ks * 4 + kq) ^ (r & 7);
                bf[nn][ks] = *(const h16x8*)(l0 + buf * BUFB + ABYTES + (r * 8 + s) * 16);
            }
    };
    auto MFMA_H = [&](int mh, h16x8 (&af)[2][2], h16x8 (&bf)[4][2]) {
        __builtin_amdgcn_s_setprio(1);
#pragma unroll
        for (int ks = 0; ks < 2; ++ks)
#pragma unroll
            for (int mm = 0; mm < 2; ++mm)
#pragma unroll
                for (int nn = 0; nn < 4; ++nn)
                    acc[mh * 2 + mm][nn] =
                        __builtin_amdgcn_mfma_f32_16x16x32_f16(
                            af[mm][ks], bf[nn][ks], acc[mh * 2 + mm][nn], 0, 0, 0);
        __builtin_amdgcn_s_setprio(0);
    };

    STAGE_B(0, 0); STAGE_AH(0, 0, 0); STAGE_AH(0, 0, 1);
    asm volatile("s_waitcnt vmcnt(2)" ::: "memory");
    __builtin_amdgcn_s_barrier();

    h16x8 af[2][2], bf[4][2];

    for (int G = 0; G < NT; ++G) {
        const int buf = G & 1;
        const int kt1 = (G + 1) << 6;
        if (G + 1 < NT) {
            STAGE_B(kt1, buf ^ 1);
            STAGE_AH(kt1, buf ^ 1, 0);
            STAGE_AH(kt1, buf ^ 1, 1);
        }
        READ_A(buf, 0, af);
        READ_B(buf, bf);
        MFMA_H(0, af, bf);
        if (G + 1 < NT) asm volatile("s_waitcnt vmcnt(8)" ::: "memory");
        else            asm volatile("s_waitcnt vmcnt(0)" ::: "memory");
        __builtin_amdgcn_s_barrier();
        READ_A(buf, 1, af);
        MFMA_H(1, af, bf);
        if (G + 1 >= NT) break;
        asm volatile("s_waitcnt vmcnt(2)" ::: "memory");
        __builtin_amdgcn_s_barrier();
    }

    const int erow = row0 + wm * 64 + (lane >> 4) * 4;
    const int ecol = col0 + wn * 64 + (lane & 15);
#pragma unroll
    for (int m = 0; m < 4; ++m)
#pragma unroll
        for (int n = 0; n < 4; ++n)
#pragma unroll
            for (int j = 0; j < 4; ++j) {
                int row = erow + m * 16 + j, col = ecol + n * 16;
                float vv = acc[m][n][j];
                if constexpr (EPI == EPI_DIV) {
                    float* C = (float*)Cv + (long long)bb * cBatch;
                    C[(size_t)row * ldc + col] = vv / rowsum[bb * SS + row];
                } else {
                    h16* C = (h16*)Cv + (long long)bb * cBatch;
                    C[(size_t)row * ldc + col] = (h16)vv;
                }
            }
}

extern "C" void kernel_launch(void* const* d_in, const int* in_sizes, int n_in,
                              void* d_out, int out_size, void* d_ws, size_t ws_size,
                              hipStream_t stream) {
    (void)in_sizes; (void)n_in; (void)out_size; (void)ws_size;
    const float* q = (const float*)d_in[0];
    const float* k = (const float*)d_in[1];
    const float* v = (const float*)d_in[2];
    const float* w = (const float*)d_in[3];
    float* out = (float*)d_out;

    const size_t QKV = (size_t)BB * SS * DD;
    h16* qh = (h16*)d_ws;            // 16 MB (reused as vpT after GEMM1 consumes q)
    h16* kh = qh + QKV;              // 16 MB
    h16* vh = kh + QKV;              // 16 MB
    h16* wh = vh + QKV;              // 2 MB
    h16* sc = wh + (size_t)DD * DD;  // E = exp(scores-16): 33.5 MB
    float* rowsum = (float*)(sc + (size_t)BB * SS * SS);   // 32 KB raw row sums

    // 1) q,k fp32->fp16 (0.125 into q); block 0 zeroes rowsum
    cvt_qk<<<2048, 256, 0, stream>>>(q, k, qh, kh, rowsum);

    // 2) GEMM1 + in-loop cvt(v,w) + epilogue rowsum atomics
    gemm1f<<<256, 512, 0, stream>>>(qh, kh, sc, v, w, vh, wh, rowsum);

    // 3) GEMM2: vpT[e][s] = sum_d W[e,d]*V[s,d]; 128^2 tiles, 512 wgs, 2/CU
    h16* vpT = qh;
    gemm2p_sm<EPI_H16><<<512, 256, 0, stream>>>(
        wh, vh, (void*)vpT, DD, DD, BB * SS, DD, /*tilesN=*/64, /*tilesMN=*/512,
        0LL, 0LL, 0LL, nullptr);

    // 4) GEMM3 + normalize: Y = (E . vpT) / rowsum
    gemm2p_sm<EPI_DIV><<<512, 256, 0, stream>>>(
        sc, vpT, (void*)out, SS, BB * SS, DD, SS, /*tilesN=*/8, /*tilesMN=*/128,
        (long long)SS * SS, (long long)SS, (long long)SS * DD, rowsum);
}

// Round 18
// 130.325 us; speedup vs baseline: 1.0117x; 1.0117x over previous
//
#include <hip/hip_runtime.h>
#include <hip/hip_fp16.h>
#include <stdint.h>

// ---- types ----
typedef _Float16 h16;
typedef _Float16 h16x8 __attribute__((ext_vector_type(8)));
typedef float f32x4 __attribute__((ext_vector_type(4)));

#define BB 4
#define SS 2048
#define DD 1024

#define EPI_H16 0
#define EPI_DIV 2   // store fp32 C / rowsum[row]  (rowsum = raw row sums)

__device__ __forceinline__ void gload16(const void* g, void* l) {
    __builtin_amdgcn_global_load_lds(
        (const __attribute__((address_space(1))) uint32_t*)g,
        (__attribute__((address_space(3))) uint32_t*)l, 16, 0, 0);
}

// ---- fp32 -> fp16 convert for q (*0.125) and k; block 0 also zeroes rowsum ----
__global__ __launch_bounds__(256) void cvt_qk(
    const float* __restrict__ q, const float* __restrict__ k,
    h16* __restrict__ qh, h16* __restrict__ kh, float* __restrict__ rowsum) {
    if (blockIdx.x == 0) {
#pragma unroll
        for (int i = 0; i < 32; ++i) rowsum[threadIdx.x + i * 256] = 0.f;
    }
    int b = blockIdx.x;
    const float* src; h16* dst; float sc = 1.0f;
    if (b < 1024)      { src = q; dst = qh; sc = 0.125f; }
    else               { src = k; dst = kh; b -= 1024; }
    size_t base = (size_t)b * 2048 + threadIdx.x;
    float4 a[8];
#pragma unroll
    for (int i = 0; i < 8; ++i) a[i] = ((const float4*)src)[base + (size_t)i * 256];
#pragma unroll
    for (int i = 0; i < 8; ++i) {
        union { int2 i2; h16 h[4]; } u;
        u.h[0] = (h16)(a[i].x * sc); u.h[1] = (h16)(a[i].y * sc);
        u.h[2] = (h16)(a[i].z * sc); u.h[3] = (h16)(a[i].w * sc);
        ((int2*)dst)[base + (size_t)i * 256] = u.i2;
    }
}

__device__ __forceinline__ void cvt_store(h16* dst, size_t g, float4 a) {
    union { int2 i2; h16 h[4]; } u;
    u.h[0] = (h16)a.x; u.h[1] = (h16)a.y; u.h[2] = (h16)a.z; u.h[3] = (h16)a.w;
    ((int2*)dst)[g] = u.i2;
}

// ==== GEMM1 (round-12 verified gemm2p<256> body) + in-loop cvt(v,w) +
//      epilogue rowsum-atomics ====
// Corrected ledger (R18): cvt issued BEFORE stage. Queue at mid wait (iter G):
//   [Ah1(G)(2, oldest), cvt(G)(2), stage(G+1)(8)] = 12 in flight.
//   mid vmcnt(10): retires exactly Ah1(G) (needed for READ_A half-1 now);
//                  fresh cvt pair and stage stay in flight -> NO latency stall.
//   end vmcnt(2):  retires cvt(G) (aged a full iter, free) + B/Ah0(G+1);
//                  keeps Ah1(G+1) in flight across the barrier (R12 pipelining).
// Robust to any compiler interleave of plain cvt ops vs builtin stages: the 2
// oldest at mid always include Ah1(G); every datum read after each barrier is
// resident in all orders. Reordering only modulates overlap, never correctness.
__global__ __launch_bounds__(512, 2) void gemm1f(
    const h16* __restrict__ A, const h16* __restrict__ B, h16* __restrict__ C,
    const float* __restrict__ v, const float* __restrict__ w,
    h16* __restrict__ vh, h16* __restrict__ wh, float* __restrict__ rowsum)
{
    constexpr int ABYTES = 256 * 128;
    constexpr int BUFB   = 2 * ABYTES;
    __shared__ __align__(1024) char lds[2 * BUFB];   // 128 KB

    const int tid = threadIdx.x;
    const int gid = blockIdx.x;                      // 0..255
    const size_t tidg = (size_t)gid * 512 + tid;     // 0..131071

    const int wgid = (gid & 7) * 32 + (gid >> 3);    // XCD swizzle (256 wgs)
    const int bb  = wgid / 64;
    const int rem = wgid % 64;
    const int tm = rem / 8, tn = rem % 8;
    const int row0 = tm * 256, col0 = tn * 256;

    const h16* Ab = A + (long long)bb * ((long long)SS * DD);
    const h16* Bb = B + (long long)bb * ((long long)SS * DD);

    const int lane = tid & 63, wid = tid >> 6;
    const int wm = wid >> 2, wn = wid & 3;
    const int frow = lane & 15, kq = lane >> 4;

    const int NT = DD >> 6;   // 16

    f32x4 acc[8][4];
#pragma unroll
    for (int m = 0; m < 8; ++m)
#pragma unroll
        for (int n = 0; n < 4; ++n) acc[m][n] = (f32x4){0.f, 0.f, 0.f, 0.f};

    char* l0 = (char*)lds;

    auto STAGE_B = [&](int kt, int buf) {
#pragma unroll
        for (int i = 0; i < 4; ++i) {
            int d = i * 512 + tid;
            int s = d & 7, r = d >> 3;
            int gg = s ^ (r & 7);
            gload16(Bb + (size_t)(col0 + r) * DD + kt + gg * 8,
                    l0 + buf * BUFB + ABYTES + (r * 8 + s) * 16);
        }
    };
    auto STAGE_AH = [&](int kt, int buf, int mh) {
#pragma unroll
        for (int i = 0; i < 2; ++i) {
            int d = i * 512 + tid;
            int s = d & 7, hr = d >> 3;
            int r = ((hr & ~63) << 1) + mh * 64 + (hr & 63);
            int gg = s ^ (r & 7);
            gload16(Ab + (size_t)(row0 + r) * DD + kt + gg * 8,
                    l0 + buf * BUFB + (r * 8 + s) * 16);
        }
    };
    auto READ_A = [&](int buf, int mh, h16x8 (&af)[4][2]) {
#pragma unroll
        for (int mm = 0; mm < 4; ++mm)
#pragma unroll
            for (int ks = 0; ks < 2; ++ks) {
                int r = wm * 128 + (mh * 4 + mm) * 16 + frow;
                int s = (ks * 4 + kq) ^ (r & 7);
                af[mm][ks] = *(const h16x8*)(l0 + buf * BUFB + (r * 8 + s) * 16);
            }
    };
    auto READ_B = [&](int buf, h16x8 (&bf)[4][2]) {
#pragma unroll
        for (int nn = 0; nn < 4; ++nn)
#pragma unroll
            for (int ks = 0; ks < 2; ++ks) {
                int r = wn * 64 + nn * 16 + frow;
                int s = (ks * 4 + kq) ^ (r & 7);
                bf[nn][ks] = *(const h16x8*)(l0 + buf * BUFB + ABYTES + (r * 8 + s) * 16);
            }
    };
    auto MFMA_H = [&](int mh, h16x8 (&af)[4][2], h16x8 (&bf)[4][2]) {
        __builtin_amdgcn_s_setprio(1);
#pragma unroll
        for (int ks = 0; ks < 2; ++ks)
#pragma unroll
            for (int mm = 0; mm < 4; ++mm)
#pragma unroll
                for (int nn = 0; nn < 4; ++nn)
                    acc[mh * 4 + mm][nn] =
                        __builtin_amdgcn_mfma_f32_16x16x32_f16(
                            af[mm][ks], bf[nn][ks], acc[mh * 4 + mm][nn], 0, 0, 0);
        __builtin_amdgcn_s_setprio(0);
    };

    // ---- prologue: w cvt (2 float4/thread, oldest ops) + stage tile 0
    {
        float4 w0 = ((const float4*)w)[tidg];
        float4 w1 = ((const float4*)w)[131072 + tidg];
        cvt_store(wh, tidg, w0);
        cvt_store(wh, 131072 + tidg, w1);
    }
    STAGE_B(0, 0); STAGE_AH(0, 0, 0); STAGE_AH(0, 0, 1);
    asm volatile("s_waitcnt vmcnt(2)" ::: "memory");
    __builtin_amdgcn_s_barrier();

    h16x8 af[4][2], bf[4][2];
    float4 vbuf;   // one-iter rotation: load at iter G, store at iter G+1

    for (int G = 0; G < NT; ++G) {
        const int buf = G & 1;
        const int kt1 = (G + 1) << 6;
        // in-loop cvt of v: 1 float4/thread/iter, issued BEFORE stage
        float4 vnew = ((const float4*)v)[(size_t)G * 131072 + tidg];
        if (G > 0) cvt_store(vh, (size_t)(G - 1) * 131072 + tidg, vbuf);
        vbuf = vnew;
        if (G + 1 < NT) {
            STAGE_B(kt1, buf ^ 1);
            STAGE_AH(kt1, buf ^ 1, 0);
            STAGE_AH(kt1, buf ^ 1, 1);
        }
        READ_A(buf, 0, af);
        READ_B(buf, bf);
        MFMA_H(0, af, bf);
        // mid: retire exactly Ah1(G) (2 oldest); cvt + stage stay in flight
        if (G + 1 < NT) asm volatile("s_waitcnt vmcnt(10)" ::: "memory");
        else            asm volatile("s_waitcnt vmcnt(0)" ::: "memory");
        __builtin_amdgcn_s_barrier();
        READ_A(buf, 1, af);
        MFMA_H(1, af, bf);
        if (G + 1 >= NT) break;
        // end: retire aged cvt(G) + B/Ah0(G+1); keep Ah1(G+1) in flight
        asm volatile("s_waitcnt vmcnt(2)" ::: "memory");
        __builtin_amdgcn_s_barrier();
    }
    // flush last v pair
    cvt_store(vh, (size_t)(NT - 1) * 131072 + tidg, vbuf);

    // ---- epilogue: E = exp(score-16) + per-row sum atomics
    h16* Cb = C + (long long)bb * ((long long)SS * SS);
    float* rs = rowsum + bb * SS;
    const int erow = row0 + wm * 128 + (lane >> 4) * 4;
    const int ecol = col0 + wn * 64 + (lane & 15);
#pragma unroll
    for (int m = 0; m < 8; ++m)
#pragma unroll
        for (int j = 0; j < 4; ++j) {
            const int row = erow + m * 16 + j;
            float p = 0.f;
#pragma unroll
            for (int n = 0; n < 4; ++n) {
                float e = __expf(acc[m][n][j] - 16.0f);
                Cb[(size_t)row * SS + (ecol + n * 16)] = (h16)e;
                p += e;
            }
            p += __shfl_xor(p, 1);
            p += __shfl_xor(p, 2);
            p += __shfl_xor(p, 4);
            p += __shfl_xor(p, 8);
            if ((lane & 15) == 0) atomicAdd(&rs[row], p);
        }
}

// ==== small GEMM (round-6/12 verified): 128x128, 4 waves, 2 blocks/CU ====
template<int EPI>
__global__ __launch_bounds__(256, 2) void gemm2p_sm(
    const h16* __restrict__ A, const h16* __restrict__ B, void* __restrict__ Cv,
    int lda, int ldb, int ldc, int K, int tilesN, int tilesMN,
    long long aBatch, long long bBatch, long long cBatch, const float* __restrict__ rowsum)
{
    constexpr int ABYTES = 128 * 128;
    constexpr int BBYTES = 128 * 128;
    constexpr int BUFB   = ABYTES + BBYTES;

    __shared__ __align__(1024) char lds[2 * BUFB];   // 64 KB

    const int tid = threadIdx.x;
    const int nwg = gridDim.x;
    const int bid = blockIdx.x;
    const int wgid = (bid & 7) * (nwg >> 3) + (bid >> 3);   // XCD swizzle
    const int bb  = wgid / tilesMN;
    const int rem = wgid % tilesMN;
    const int tm = rem / tilesN, tn = rem % tilesN;
    const int row0 = tm * 128, col0 = tn * 128;

    const h16* Ab = A + (long long)bb * aBatch;
    const h16* Bb = B + (long long)bb * bBatch;

    const int lane = tid & 63, wid = tid >> 6;
    const int wm = wid >> 1, wn = wid & 1;
    const int frow = lane & 15, kq = lane >> 4;

    const int NT = K >> 6;

    f32x4 acc[4][4];
#pragma unroll
    for (int m = 0; m < 4; ++m)
#pragma unroll
        for (int n = 0; n < 4; ++n) acc[m][n] = (f32x4){0.f, 0.f, 0.f, 0.f};

    char* l0 = (char*)lds;

    auto STAGE_B = [&](int kt, int buf) {
#pragma unroll
        for (int i = 0; i < 4; ++i) {
            int d = i * 256 + tid;
            int s = d & 7, r = d >> 3;
            int gg = s ^ (r & 7);
            gload16(Bb + (size_t)(col0 + r) * ldb + kt + gg * 8,
                    l0 + buf * BUFB + ABYTES + (r * 8 + s) * 16);
        }
    };
    auto STAGE_AH = [&](int kt, int buf, int mh) {
#pragma unroll
        for (int i = 0; i < 2; ++i) {
            int d = i * 256 + tid;
            int s = d & 7, hr = d >> 3;
            int r = ((hr & ~31) << 1) + mh * 32 + (hr & 31);
            int gg = s ^ (r & 7);
            gload16(Ab + (size_t)(row0 + r) * lda + kt + gg * 8,
                    l0 + buf * BUFB + (r * 8 + s) * 16);
        }
    };
    auto READ_A = [&](int buf, int mh, h16x8 (&af)[2][2]) {
#pragma unroll
        for (int mm = 0; mm < 2; ++mm)
#pragma unroll
            for (int ks = 0; ks < 2; ++ks) {
                int r = wm * 64 + (mh * 2 + mm) * 16 + frow;
                int s = (ks * 4 + kq) ^ (r & 7);
                af[mm][ks] = *(const h16x8*)(l0 + buf * BUFB + (r * 8 + s) * 16);
            }
    };
    auto READ_B = [&](int buf, h16x8 (&bf)[4][2]) {
#pragma unroll
        for (int nn = 0; nn < 4; ++nn)
#pragma unroll
            for (int ks = 0; ks < 2; ++ks) {
                int r = wn * 64 + nn * 16 + frow;
                int s = (ks * 4 + kq) ^ (r & 7);
                bf[nn][ks] = *(const h16x8*)(l0 + buf * BUFB + ABYTES + (r * 8 + s) * 16);
            }
    };
    auto MFMA_H = [&](int mh, h16x8 (&af)[2][2], h16x8 (&bf)[4][2]) {
        __builtin_amdgcn_s_setprio(1);
#pragma unroll
        for (int ks = 0; ks < 2; ++ks)
#pragma unroll
            for (int mm = 0; mm < 2; ++mm)
#pragma unroll
                for (int nn = 0; nn < 4; ++nn)
                    acc[mh * 2 + mm][nn] =
                        __builtin_amdgcn_mfma_f32_16x16x32_f16(
                            af[mm][ks], bf[nn][ks], acc[mh * 2 + mm][nn], 0, 0, 0);
        __builtin_amdgcn_s_setprio(0);
    };

    STAGE_B(0, 0); STAGE_AH(0, 0, 0); STAGE_AH(0, 0, 1);
    asm volatile("s_waitcnt vmcnt(2)" ::: "memory");
    __builtin_amdgcn_s_barrier();

    h16x8 af[2][2], bf[4][2];

    for (int G = 0; G < NT; ++G) {
        const int buf = G & 1;
        const int kt1 = (G + 1) << 6;
        if (G + 1 < NT) {
            STAGE_B(kt1, buf ^ 1);
            STAGE_AH(kt1, buf ^ 1, 0);
            STAGE_AH(kt1, buf ^ 1, 1);
        }
        READ_A(buf, 0, af);
        READ_B(buf, bf);
        MFMA_H(0, af, bf);
        if (G + 1 < NT) asm volatile("s_waitcnt vmcnt(8)" ::: "memory");
        else            asm volatile("s_waitcnt vmcnt(0)" ::: "memory");
        __builtin_amdgcn_s_barrier();
        READ_A(buf, 1, af);
        MFMA_H(1, af, bf);
        if (G + 1 >= NT) break;
        asm volatile("s_waitcnt vmcnt(2)" ::: "memory");
        __builtin_amdgcn_s_barrier();
    }

    const int erow = row0 + wm * 64 + (lane >> 4) * 4;
    const int ecol = col0 + wn * 64 + (lane & 15);
#pragma unroll
    for (int m = 0; m < 4; ++m)
#pragma unroll
        for (int n = 0; n < 4; ++n)
#pragma unroll
            for (int j = 0; j < 4; ++j) {
                int row = erow + m * 16 + j, col = ecol + n * 16;
                float vv = acc[m][n][j];
                if constexpr (EPI == EPI_DIV) {
                    float* C = (float*)Cv + (long long)bb * cBatch;
                    C[(size_t)row * ldc + col] = vv / rowsum[bb * SS + row];
                } else {
                    h16* C = (h16*)Cv + (long long)bb * cBatch;
                    C[(size_t)row * ldc + col] = (h16)vv;
                }
            }
}

extern "C" void kernel_launch(void* const* d_in, const int* in_sizes, int n_in,
                              void* d_out, int out_size, void* d_ws, size_t ws_size,
                              hipStream_t stream) {
    (void)in_sizes; (void)n_in; (void)out_size; (void)ws_size;
    const float* q = (const float*)d_in[0];
    const float* k = (const float*)d_in[1];
    const float* v = (const float*)d_in[2];
    const float* w = (const float*)d_in[3];
    float* out = (float*)d_out;

    const size_t QKV = (size_t)BB * SS * DD;
    h16* qh = (h16*)d_ws;            // 16 MB (reused as vpT after GEMM1 consumes q)
    h16* kh = qh + QKV;              // 16 MB
    h16* vh = kh + QKV;              // 16 MB
    h16* wh = vh + QKV;              // 2 MB
    h16* sc = wh + (size_t)DD * DD;  // E = exp(scores-16): 33.5 MB
    float* rowsum = (float*)(sc + (size_t)BB * SS * SS);   // 32 KB raw row sums

    // 1) q,k fp32->fp16 (0.125 into q); block 0 zeroes rowsum
    cvt_qk<<<2048, 256, 0, stream>>>(q, k, qh, kh, rowsum);

    // 2) GEMM1 + in-loop cvt(v,w) + epilogue rowsum atomics
    gemm1f<<<256, 512, 0, stream>>>(qh, kh, sc, v, w, vh, wh, rowsum);

    // 3) GEMM2: vpT[e][s] = sum_d W[e,d]*V[s,d]; 128^2 tiles, 512 wgs, 2/CU
    h16* vpT = qh;
    gemm2p_sm<EPI_H16><<<512, 256, 0, stream>>>(
        wh, vh, (void*)vpT, DD, DD, BB * SS, DD, /*tilesN=*/64, /*tilesMN=*/512,
        0LL, 0LL, 0LL, nullptr);

    // 4) GEMM3 + normalize: Y = (E . vpT) / rowsum
    gemm2p_sm<EPI_DIV><<<512, 256, 0, stream>>>(
        sc, vpT, (void*)out, SS, BB * SS, DD, SS, /*tilesN=*/8, /*tilesMN=*/128,
        (long long)SS * SS, (long long)SS, (long long)SS * DD, rowsum);
}